// Round 5
// baseline (363.406 us; speedup 1.0000x reference)
//
#include <hip/hip_runtime.h>
#include <hip/hip_bf16.h>
#include <stdint.h>

typedef __hip_bfloat16 bf16;
typedef __bf16 bf16x8 __attribute__((ext_vector_type(8)));
typedef float f32x4 __attribute__((ext_vector_type(4)));

#define B_ 2
#define T_ 2048
#define HID_ 2048
#define H_ 16
#define D_ 128
#define WIN_ 512

// ---- async global->LDS, 16B per lane (lds dest = wave-uniform base + lane*16) ----
__device__ __forceinline__ void async_copy16(const void* g, void* l) {
  __builtin_amdgcn_global_load_lds(
      (__attribute__((address_space(1))) void*)(uintptr_t)g,
      (__attribute__((address_space(3))) void*)(uint32_t)(uintptr_t)l,
      16, 0, 0);
}

// raw workgroup barrier with compiler memory fences (no vmcnt/lgkm drain)
__device__ __forceinline__ void block_sync() {
  asm volatile("" ::: "memory");
  __builtin_amdgcn_s_barrier();
  asm volatile("" ::: "memory");
}

// =================== fused fp32->bf16 (h and w1 in one launch) ===================
__global__ __launch_bounds__(256) void cvt4_all(
    const float* __restrict__ h, const float* __restrict__ w1, bf16* __restrict__ outh, bf16* __restrict__ outw1)
{
  int i = blockIdx.x * 256 + threadIdx.x;
  const int NH = 2097152;            // h: 2*2048*2048 /4
  const float* in; bf16* out;
  if (i < NH) { in = h; out = outh; }
  else { i -= NH; in = w1; out = outw1; }   // w1: 4*512*2048 /4 = 1048576
  const float4 v = ((const float4*)in)[i];
  bf16* p = out + (size_t)i * 4;
  p[0] = __float2bfloat16(v.x);
  p[1] = __float2bfloat16(v.y);
  p[2] = __float2bfloat16(v.z);
  p[3] = __float2bfloat16(v.w);
}

// =================== fused fp32->bf16 + transpose, 4 weight matrices in one launch ===================
__global__ __launch_bounds__(256) void cvtT_all(
    const float* __restrict__ wqc, const float* __restrict__ wk, const float* __restrict__ wv,
    const float* __restrict__ wqu, bf16* __restrict__ qkvT, bf16* __restrict__ wquT)
{
  __shared__ bf16 tile[32][33];
  const int id = blockIdx.x;
  const float* in; bf16* out; int R, C, bx, by;
  if (id < 1024)      { int l = id;        in = wqc; out = qkvT;                      R = 2048; C = 512;  bx = (l & 15) * 32; by = (l >> 4) * 32; }
  else if (id < 1280) { int l = id - 1024; in = wk;  out = qkvT + (size_t)512 * 2048; R = 2048; C = 128;  bx = (l & 3) * 32;  by = (l >> 2) * 32; }
  else if (id < 1536) { int l = id - 1280; in = wv;  out = qkvT + (size_t)640 * 2048; R = 2048; C = 128;  bx = (l & 3) * 32;  by = (l >> 2) * 32; }
  else                { int l = id - 1536; in = wqu; out = wquT;                      R = 512;  C = 2048; bx = (l & 63) * 32; by = (l >> 6) * 32; }
  const int tx = threadIdx.x & 31, ty = threadIdx.x >> 5;
#pragma unroll
  for (int i = 0; i < 32; i += 8)
    tile[ty+i][tx] = __float2bfloat16(in[(size_t)(by + ty + i)*C + bx + tx]);
  __syncthreads();
#pragma unroll
  for (int i = 0; i < 32; i += 8)
    out[(size_t)(bx + ty + i)*R + by + tx] = tile[tx][ty+i];
}

// =================== single fp32->bf16 transpose (w2) ===================
__global__ __launch_bounds__(256) void cvtT(
    const float* __restrict__ in, bf16* __restrict__ out, int R, int C)
{
  __shared__ bf16 tile[32][33];
  const int bx = blockIdx.x*32, by = blockIdx.y*32;
  const int tx = threadIdx.x & 31, ty = threadIdx.x >> 5;
#pragma unroll
  for (int i = 0; i < 32; i += 8)
    tile[ty+i][tx] = __float2bfloat16(in[(size_t)(by + ty + i)*C + bx + tx]);
  __syncthreads();
#pragma unroll
  for (int i = 0; i < 32; i += 8)
    out[(size_t)(bx + ty + i)*R + by + tx] = tile[tx][ty+i];
}

// =================== bf16 transpose: out[C][R] = in[R][C]^T (batched via z) ===================
__global__ __launch_bounds__(256) void transpose_k(
    const bf16* __restrict__ in, bf16* __restrict__ out,
    int R, int C, int ldin, int ldout, long long inBatch, long long outBatch)
{
  __shared__ bf16 tile[32][33];
  in  += (size_t)blockIdx.z * inBatch;
  out += (size_t)blockIdx.z * outBatch;
  const int bx = blockIdx.x*32, by = blockIdx.y*32;
  const int tx = threadIdx.x & 31, ty = threadIdx.x >> 5;
#pragma unroll
  for (int i = 0; i < 32; i += 8)
    tile[ty+i][tx] = in[(size_t)(by + ty + i)*ldin + bx + tx];
  __syncthreads();
#pragma unroll
  for (int i = 0; i < 32; i += 8)
    out[(size_t)(bx + ty + i)*ldout + by + tx] = tile[tx][ty+i];
}

// =================== bf16 GEMM (m97 structure): C[M,N] = A[M,K] * BT[N,K]^T ===================
// used for: qkv GEMM (N=768 -> 192 blocks) and Weff GEMM (grid (16,4,4)=256 blocks -- full
// CU coverage; the former (8,4,4) gemm_bt8 grid left half the chip idle at 1 block/CU).
template <bool F32OUT>
__global__ __launch_bounds__(256) void gemm_bt(
    const bf16* __restrict__ Ab, const bf16* __restrict__ Bb, void* __restrict__ Cb,
    int K, int lda, int ldb, int ldc,
    long long sAz, long long sBz, long long sCz)
{
  const bf16* A = Ab + (size_t)blockIdx.z * sAz;
  const bf16* B = Bb + (size_t)blockIdx.z * sBz;
  __shared__ __align__(16) __bf16 sa[128*64];
  __shared__ __align__(16) __bf16 sb[128*64];
  const int bm = blockIdx.x * 128, bn = blockIdx.y * 128;
  const int t = threadIdx.x;
  const int wave = t >> 6, lane = t & 63;
  const int fm = lane & 15, quad = lane >> 4;
  const int wm = (wave & 1) * 64, wn = (wave >> 1) * 64;
  const int arow0 = t >> 3;
  const int acol_sw = (((t & 7) ^ (arow0 & 7)) << 3);
  const int fsw = fm & 7;

  f32x4 acc[4][4];
#pragma unroll
  for (int i = 0; i < 4; ++i)
#pragma unroll
    for (int j = 0; j < 4; ++j) acc[i][j] = {0.f, 0.f, 0.f, 0.f};

  for (int k0 = 0; k0 < K; k0 += 64) {
    __syncthreads();
#pragma unroll
    for (int i = 0; i < 4; ++i)
      async_copy16(&A[(size_t)(bm + arow0 + i*32)*lda + k0 + acol_sw], &sa[(size_t)(i*256 + wave*64)*8]);
#pragma unroll
    for (int i = 0; i < 4; ++i)
      async_copy16(&B[(size_t)(bn + arow0 + i*32)*ldb + k0 + acol_sw], &sb[(size_t)(i*256 + wave*64)*8]);
    __syncthreads();
#pragma unroll
    for (int ks = 0; ks < 64; ks += 32) {
      bf16x8 av[4], bv[4];
#pragma unroll
      for (int mt = 0; mt < 4; ++mt)
        av[mt] = *(const bf16x8*)&sa[(wm + mt*16 + fm)*64 + ((((ks>>3) + quad) ^ fsw) << 3)];
#pragma unroll
      for (int nt = 0; nt < 4; ++nt)
        bv[nt] = *(const bf16x8*)&sb[(wn + nt*16 + fm)*64 + ((((ks>>3) + quad) ^ fsw) << 3)];
#pragma unroll
      for (int mt = 0; mt < 4; ++mt)
#pragma unroll
        for (int nt = 0; nt < 4; ++nt)
          acc[mt][nt] = __builtin_amdgcn_mfma_f32_16x16x32_bf16(av[mt], bv[nt], acc[mt][nt], 0, 0, 0);
    }
  }
  if constexpr (F32OUT) {
    float* C = (float*)Cb + (size_t)blockIdx.z * sCz;
#pragma unroll
    for (int mt = 0; mt < 4; ++mt)
#pragma unroll
      for (int r = 0; r < 4; ++r) {
        const int row = bm + wm + mt*16 + quad*4 + r;
#pragma unroll
        for (int nt = 0; nt < 4; ++nt)
          C[(size_t)row*ldc + bn + wn + nt*16 + fm] = acc[mt][nt][r];
      }
  } else {
    bf16* C = (bf16*)Cb + (size_t)blockIdx.z * sCz;
#pragma unroll
    for (int mt = 0; mt < 4; ++mt)
#pragma unroll
      for (int r = 0; r < 4; ++r) {
        const int row = bm + wm + mt*16 + quad*4 + r;
#pragma unroll
        for (int nt = 0; nt < 4; ++nt)
          C[(size_t)row*ldc + bn + wn + nt*16 + fm] = __float2bfloat16(acc[mt][nt][r]);
      }
  }
}

// =================== pipelined GEMM v2: 2 phases/K-tile, 16 MFMA/phase ===================
// BM=256, BN=128, BK=64; 512 threads = 8 waves; counted vmcnt(2) once per K-tile;
// XCD-chunked bijective blockIdx swizzle (T1) for B-panel L2 locality.
template <bool F32OUT>
__global__ __launch_bounds__(512, 2) void gemm_bt8(
    const bf16* __restrict__ Ab, const bf16* __restrict__ Bb, void* __restrict__ Cb,
    int K, int lda, int ldb, int ldc,
    long long sAz, long long sBz, long long sCz)
{
  const bf16* A = Ab + (size_t)blockIdx.z * sAz;
  const bf16* B = Bb + (size_t)blockIdx.z * sBz;
  __shared__ __align__(16) __bf16 sA[2][256*64];
  __shared__ __align__(16) __bf16 sB[2][128*64];
  // bijective XCD-chunk swizzle (m204 form; exact when nwg%8==0)
  const int nx = gridDim.x, nwg = nx * gridDim.y;
  const int wg = blockIdx.x + nx * blockIdx.y;
  const int xcd = wg & 7, qd = nwg >> 3, rm = nwg & 7;
  const int swz = (xcd < rm ? xcd * (qd + 1) : rm * (qd + 1) + (xcd - rm) * qd) + (wg >> 3);
  const int bm = (swz % nx) * 256, bn = (swz / nx) * 128;
  const int t = threadIdx.x;
  const int wave = t >> 6, lane = t & 63;
  const int fm = lane & 15, quad = lane >> 4, fsw = fm & 7;
  const int wave_m = wave >> 1, wave_n = wave & 1;
  const int srow = t >> 3;                      // staging row within a 64-row granule
  const int cchunk = (t & 7) ^ (srow & 7);      // pre-swizzled source chunk (inverse of read XOR)
  const int NT = K >> 6;                        // number of K-tiles (NT >= 2 required)

  auto stage = [&](int tile, int o) {           // o: 0=Bh0 1=Bh1 2=Ah0 3=Ah1
    if (tile >= NT) return;
    const int par = tile & 1;
    const int kc = (tile << 6) + (cchunk << 3);
    if (o < 2) {
      async_copy16(&B[(size_t)(bn + (o << 6) + srow)*ldb + kc],
                   &sB[par][(size_t)((o << 6) + wave*8) * 64]);
    } else {
      const int h = (o - 2) << 7;
      async_copy16(&A[(size_t)(bm + h + srow)*lda + kc],
                   &sA[par][(size_t)(h + wave*8) * 64]);
      async_copy16(&A[(size_t)(bm + h + 64 + srow)*lda + kc],
                   &sA[par][(size_t)(h + 64 + wave*8) * 64]);
    }
  };

  f32x4 acc[4][4];
#pragma unroll
  for (int i = 0; i < 4; ++i)
#pragma unroll
    for (int j = 0; j < 4; ++j) acc[i][j] = {0.f, 0.f, 0.f, 0.f};

  // prologue: A(0) 4, B(0) 2 (oldest 6), then B(1) 2; vmcnt(2) leaves B(1) in flight
  stage(0, 2); stage(0, 3); stage(0, 0); stage(0, 1);
  stage(1, 0); stage(1, 1);
  asm volatile("s_waitcnt vmcnt(2)" ::: "memory");
  block_sync();

  for (int d = 0; d < NT; ++d) {
    const int par = d & 1;
    bf16x8 bfr[4][2], a01[2][2], a23[2][2];
    // ---------------- phase 0: q-subtiles 0,1 ----------------
#pragma unroll
    for (int n = 0; n < 4; ++n) {
      const int brow = wave_n*64 + n*16 + fm;
      bfr[n][0] = *(const bf16x8*)&sB[par][(size_t)brow*64 + ((quad ^ fsw) << 3)];
      bfr[n][1] = *(const bf16x8*)&sB[par][(size_t)brow*64 + (((4 + quad) ^ fsw) << 3)];
    }
#pragma unroll
    for (int qq = 0; qq < 2; ++qq) {
      const int arow = wave_m*64 + qq*16 + fm;
      a01[qq][0] = *(const bf16x8*)&sA[par][(size_t)arow*64 + ((quad ^ fsw) << 3)];
      a01[qq][1] = *(const bf16x8*)&sA[par][(size_t)arow*64 + (((4 + quad) ^ fsw) << 3)];
    }
    stage(d + 1, 2); stage(d + 1, 3);
    block_sync();
    __builtin_amdgcn_s_setprio(1);
#pragma unroll
    for (int qq = 0; qq < 2; ++qq)
#pragma unroll
      for (int n = 0; n < 4; ++n) {
        acc[qq][n] = __builtin_amdgcn_mfma_f32_16x16x32_bf16(a01[qq][0], bfr[n][0], acc[qq][n], 0, 0, 0);
        acc[qq][n] = __builtin_amdgcn_mfma_f32_16x16x32_bf16(a01[qq][1], bfr[n][1], acc[qq][n], 0, 0, 0);
      }
    __builtin_amdgcn_s_setprio(0);
    block_sync();
    // ---------------- phase 1: q-subtiles 2,3 ----------------
#pragma unroll
    for (int qq = 0; qq < 2; ++qq) {
      const int arow = wave_m*64 + (2 + qq)*16 + fm;
      a23[qq][0] = *(const bf16x8*)&sA[par][(size_t)arow*64 + ((quad ^ fsw) << 3)];
      a23[qq][1] = *(const bf16x8*)&sA[par][(size_t)arow*64 + (((4 + quad) ^ fsw) << 3)];
    }
    stage(d + 2, 0); stage(d + 2, 1);
    block_sync();
    __builtin_amdgcn_s_setprio(1);
#pragma unroll
    for (int qq = 0; qq < 2; ++qq)
#pragma unroll
      for (int n = 0; n < 4; ++n) {
        acc[2+qq][n] = __builtin_amdgcn_mfma_f32_16x16x32_bf16(a23[qq][0], bfr[n][0], acc[2+qq][n], 0, 0, 0);
        acc[2+qq][n] = __builtin_amdgcn_mfma_f32_16x16x32_bf16(a23[qq][1], bfr[n][1], acc[2+qq][n], 0, 0, 0);
      }
    __builtin_amdgcn_s_setprio(0);
    if (d < NT - 1) {                     // per-K-tile checkpoint guarding tile d+1
      if (d == NT - 2) asm volatile("s_waitcnt vmcnt(0)" ::: "memory");
      else             asm volatile("s_waitcnt vmcnt(2)" ::: "memory");
    }
    block_sync();
  }

  if constexpr (F32OUT) {
    float* C = (float*)Cb + (size_t)blockIdx.z * sCz;
#pragma unroll
    for (int q = 0; q < 4; ++q)
#pragma unroll
      for (int r = 0; r < 4; ++r) {
        const int row = bm + wave_m*64 + q*16 + quad*4 + r;
#pragma unroll
        for (int n = 0; n < 4; ++n)
          C[(size_t)row*ldc + bn + wave_n*64 + n*16 + fm] = acc[q][n][r];
      }
  } else {
    bf16* C = (bf16*)Cb + (size_t)blockIdx.z * sCz;
#pragma unroll
    for (int q = 0; q < 4; ++q)
#pragma unroll
      for (int r = 0; r < 4; ++r) {
        const int row = bm + wave_m*64 + q*16 + quad*4 + r;
#pragma unroll
        for (int n = 0; n < 4; ++n)
          C[(size_t)row*ldc + bn + wave_n*64 + n*16 + fm] = __float2bfloat16(acc[q][n][r]);
      }
  }
}

// =================== fused partial-RoPE + RMSNorm, q and k paths in one launch ===================
__global__ __launch_bounds__(256) void rope_rms_all(
    const bf16* __restrict__ qin, bf16* __restrict__ qout, const float* __restrict__ qw,
    const bf16* __restrict__ kin, bf16* __restrict__ kout, const float* __restrict__ kw)
{
  int blk = blockIdx.x;
  const bf16* in; bf16* out; const float* w; int in_stride, t_shift; float oscale;
  if (blk < 16384) { in = qin; out = qout; w = qw; in_stride = 128; t_shift = 4; oscale = 0.12751744f; }
  else { blk -= 16384; in = kin; out = kout; w = kw; in_stride = 768; t_shift = 0; oscale = 1.0f; }
  const int rid = blk*4 + (threadIdx.x >> 6);
  const int lane = threadIdx.x & 63;
  const bf16* row = in + (size_t)rid * in_stride;
  float e0 = __bfloat162float(row[lane]);
  float e1 = __bfloat162float(row[lane + 64]);
  float s2 = e0*e0 + e1*e1;
#pragma unroll
  for (int off = 32; off; off >>= 1) s2 += __shfl_xor(s2, off);
  const float rms = rsqrtf(s2 * (1.f/128.f) + 1e-6f) * oscale;
  const int tpos = (rid >> t_shift) & (T_ - 1);
  const int i = lane & 31;
  const float inv = expf(-(float)i * 0.28782313662425574f);  // ln(10000)/32
  const float ang = (float)tpos * inv;
  float sn, c;
  sincosf(ang, &sn, &c);
  const float other = __shfl_xor(e0, 32);
  const float r0 = (lane < 32) ? (e0*c - other*sn) : (other*sn + e0*c);
  bf16* orow = out + (size_t)rid * 128;
  orow[lane]      = __float2bfloat16(r0 * rms * w[lane]);
  orow[lane + 64] = __float2bfloat16(e1 * rms * w[lane + 64]);
}

// =================== sliding-window flash attention (MQA, sink, max-free, in-register P) ===================
// Swapped QK^T: lane(fm,quad) holds P[q=fm][k=16nt+4quad+r]. Full T12: P goes to the PV
// A-operand ENTIRELY in registers via 12 shfl_xor (XOR 16/32/48) of the cvt_pk words --
// no P LDS round-trip, no lgkm drain, and only 2 barriers/tile (post-write + end-of-tile).
// Derivation: PV A-operand for lane(fm,quad), ks: words w0..3 = P[q=fm][k=32ks+8quad+2w..],
// i.e. pk[nt=2ks+(quad>>1)] from source quads 2(quad&1) (w0,w1) and 2(quad&1)+1 (w2,w3).
// Movements: pk[0],pk[2]: (q0->t0 own),(q1->t0 x16),(q2->t1 x48),(q3->t1 x32);
//            pk[1],pk[3]: (q0->t2 x32),(q1->t2 x48),(q2->t3 x16),(q3->t3 own).
__global__ __launch_bounds__(256, 3) void attn_kernel(
    const bf16* __restrict__ q,     // [B,T,H*D]  (pre-scaled by 1/(sqrt(D)ln2))
    const bf16* __restrict__ k,     // [B,T,D]
    const bf16* __restrict__ vt,    // [B,D,T]
    const float* __restrict__ sink, // [H]
    bf16* __restrict__ o)           // [B,T,H*D]
{
  __shared__ __align__(16) __bf16 sQ[64*128];   // 16 chunk-slots/row, swizzled ^(r&7)
  __shared__ __align__(16) __bf16 sK[64*128];
  __shared__ __align__(16) __bf16 sV[128*64];   // [d][s], 8 slots/row, swizzled ^(d&7)
  const int qt = blockIdx.x, h = blockIdx.y, b = blockIdx.z;
  const int qb = qt * 64;
  const int t = threadIdx.x, wave = t >> 6, lane = t & 63;
  const int fm = lane & 15, quad = lane >> 4;
  const int fsw = fm & 7;
  const int qw = qb + wave*16;

#pragma unroll
  for (int i = 0; i < 4; ++i) {   // stage Q once (async, source-swizzled)
    int chunk = i*256 + t;
    int r = chunk >> 4, c8 = (chunk & 15) ^ (r & 7);
    async_copy16(&q[(size_t)((b*T_ + qb + r)*H_ + h)*D_ + c8*8], &sQ[(size_t)(i*256 + wave*64)*8]);
  }

  bf16x8 kreg[4], vreg[4];
  auto load_kv = [&](int kb) {     // source-swizzled (same layout the DMA produced)
#pragma unroll
    for (int i = 0; i < 4; ++i) {
      int chunk = i*256 + t;
      int r = chunk >> 4, c8 = (chunk & 15) ^ (r & 7);
      kreg[i] = *(const bf16x8*)&k[(size_t)(b*T_ + kb + r)*D_ + c8*8];
    }
#pragma unroll
    for (int i = 0; i < 4; ++i) {
      int chunk = i*256 + t;
      int d = chunk >> 3, c8 = (chunk & 7) ^ (d & 7);
      vreg[i] = *(const bf16x8*)&vt[(size_t)(b*D_ + d)*T_ + kb + c8*8];
    }
  };

  float l_part = 0.f;             // partial softmax denom for q = qb + wave*16 + fm
  f32x4 oacc[8];
#pragma unroll
  for (int i = 0; i < 8; ++i) oacc[i] = {0.f, 0.f, 0.f, 0.f};

  int lo = qb - (WIN_ - 1); if (lo < 0) lo = 0;
  const int kt0 = lo >> 6;
  load_kv(kt0 * 64);              // prologue prefetch

  for (int kt = kt0; kt <= qt; ++kt) {
    const int kb = kt * 64;
#pragma unroll
    for (int i = 0; i < 4; ++i)   // compiler inserts counted vmcnt wait for kreg here
      *(bf16x8*)&sK[(size_t)(i*256 + t)*8] = kreg[i];
#pragma unroll
    for (int i = 0; i < 4; ++i)
      *(bf16x8*)&sV[(size_t)(i*256 + t)*8] = vreg[i];
    asm volatile("s_waitcnt lgkmcnt(0)" ::: "memory");
    block_sync();                 // K/V (and Q, 1st iter) visible to all waves
    if (kt < qt) load_kv(kb + 64);  // prefetch next tile under QK+softmax+PV

    // S^T strip: s[nt][r] = S[k = kb+nt*16+quad*4+r][q = qb+wave*16+fm]  (swapped operands)
    f32x4 s[4];
#pragma unroll
    for (int nt = 0; nt < 4; ++nt) s[nt] = {0.f, 0.f, 0.f, 0.f};
#pragma unroll
    for (int ds = 0; ds < 4; ++ds) {
      bf16x8 aq = *(const bf16x8*)&sQ[(wave*16 + fm)*128 + (((ds*4 + quad) ^ fsw) << 3)];
#pragma unroll
      for (int nt = 0; nt < 4; ++nt) {
        bf16x8 bk = *(const bf16x8*)&sK[(nt*16 + fm)*128 + (((ds*4 + quad) ^ fsw) << 3)];
        s[nt] = __builtin_amdgcn_mfma_f32_16x16x32_bf16(bk, aq, s[nt], 0, 0, 0);  // SWAPPED
      }
    }

    const bool interior = (kb + 63 <= qw) && (kb >= qw - (WIN_ - 16));
    if (!interior) {
      const int qi = qb + wave*16 + fm;
#pragma unroll
      for (int nt = 0; nt < 4; ++nt)
#pragma unroll
        for (int r = 0; r < 4; ++r) {
          const int ki = kb + nt*16 + quad*4 + r;
          const bool ok = (ki <= qi) && (qi - ki < WIN_);
          s[nt][r] = ok ? s[nt][r] : -1e30f;
        }
    }
    uint32_t pkx[4], pky[4];
#pragma unroll
    for (int nt = 0; nt < 4; ++nt) {
#pragma unroll
      for (int r = 0; r < 4; ++r) {
        s[nt][r] = __builtin_exp2f(s[nt][r]);
        l_part += s[nt][r];
      }
      asm("v_cvt_pk_bf16_f32 %0, %1, %2" : "=v"(pkx[nt]) : "v"(s[nt][0]), "v"(s[nt][1]));
      asm("v_cvt_pk_bf16_f32 %0, %1, %2" : "=v"(pky[nt]) : "v"(s[nt][2]), "v"(s[nt][3]));
    }
    // ---- in-register P redistribution (12 shfl_xor, no LDS) ----
    const bool hi  = quad >= 2;          // quads 2,3
    const bool odd = (quad & 1) != 0;    // quads 1,3
    // senders: XOR16: q1->pk0/2, q2->pk1/3 ; XOR48: q2->pk0/2, q1->pk1/3 ; XOR32: q3->pk0/2, q0->pk1/3
    uint32_t s16x = hi ? pkx[1] : pkx[0], s16y = hi ? pky[1] : pky[0];
    uint32_t s16X = hi ? pkx[3] : pkx[2], s16Y = hi ? pky[3] : pky[2];
    uint32_t s48x = hi ? pkx[0] : pkx[1], s48y = hi ? pky[0] : pky[1];
    uint32_t s48X = hi ? pkx[2] : pkx[3], s48Y = hi ? pky[2] : pky[3];
    uint32_t s32x = odd ? pkx[0] : pkx[1], s32y = odd ? pky[0] : pky[1];
    uint32_t s32X = odd ? pkx[2] : pkx[3], s32Y = odd ? pky[2] : pky[3];
    uint32_t r16x = __shfl_xor((int)s16x, 16), r16y = __shfl_xor((int)s16y, 16);
    uint32_t r16X = __shfl_xor((int)s16X, 16), r16Y = __shfl_xor((int)s16Y, 16);
    uint32_t r48x = __shfl_xor((int)s48x, 48), r48y = __shfl_xor((int)s48y, 48);
    uint32_t r48X = __shfl_xor((int)s48X, 48), r48Y = __shfl_xor((int)s48Y, 48);
    uint32_t r32x = __shfl_xor((int)s32x, 32), r32y = __shfl_xor((int)s32y, 32);
    uint32_t r32X = __shfl_xor((int)s32X, 32), r32Y = __shfl_xor((int)s32Y, 32);
    // receivers: q0: A=own pk0/2, B=r16 ; q1: A=r48, B=r32 ; q2: A=r32, B=r48 ; q3: A=r16, B=own pk1/3
    union { uint32_t u[4]; bf16x8 v; } ap0, ap1;
    ap0.u[0] = odd ? (hi ? r16x : r48x) : (hi ? r32x : pkx[0]);
    ap0.u[1] = odd ? (hi ? r16y : r48y) : (hi ? r32y : pky[0]);
    ap0.u[2] = odd ? (hi ? pkx[1] : r32x) : (hi ? r48x : r16x);
    ap0.u[3] = odd ? (hi ? pky[1] : r32y) : (hi ? r48y : r16y);
    ap1.u[0] = odd ? (hi ? r16X : r48X) : (hi ? r32X : pkx[2]);
    ap1.u[1] = odd ? (hi ? r16Y : r48Y) : (hi ? r32Y : pky[2]);
    ap1.u[2] = odd ? (hi ? pkx[3] : r32X) : (hi ? r48X : r16X);
    ap1.u[3] = odd ? (hi ? pky[3] : r32Y) : (hi ? r48Y : r16Y);
    // O += P V   (ks=0 uses ap0, ks=1 uses ap1; V frags from LDS as before)
#pragma unroll
    for (int nt = 0; nt < 8; ++nt) {
      bf16x8 bv = *(const bf16x8*)&sV[(nt*16 + fm)*64 + ((quad ^ fsw) << 3)];
      oacc[nt] = __builtin_amdgcn_mfma_f32_16x16x32_bf16(ap0.v, bv, oacc[nt], 0, 0, 0);
    }
#pragma unroll
    for (int nt = 0; nt < 8; ++nt) {
      bf16x8 bv = *(const bf16x8*)&sV[(nt*16 + fm)*64 + (((4 + quad) ^ fsw) << 3)];
      oacc[nt] = __builtin_amdgcn_mfma_f32_16x16x32_bf16(ap1.v, bv, oacc[nt], 0, 0, 0);
    }
    block_sync();                 // all QK/PV reads done before next tile's K/V ds_writes
  }
  // reduce l across quads (lanes with same fm), then redistribute to output rows
  l_part += __shfl_xor(l_part, 16);
  l_part += __shfl_xor(l_part, 32);   // now l_part = L[q = qb + wave*16 + fm]
  const float sink_p = __builtin_exp2f(sink[h] * 1.4426950408889634f);
#pragma unroll
  for (int r = 0; r < 4; ++r) {
    const int qi = qb + wave*16 + quad*4 + r;
    const float inv_l = 1.f / (__shfl(l_part, quad*4 + r) + sink_p);
#pragma unroll
    for (int nt = 0; nt < 8; ++nt) {
      const int d = nt*16 + fm;
      o[(size_t)(b*T_ + qi)*(H_*D_) + h*D_ + d] = __float2bfloat16(oacc[nt][r] * inv_l);
    }
  }
}

// =========================================================================================
extern "C" void kernel_launch(void* const* d_in, const int* in_sizes, int n_in,
                              void* d_out, int out_size, void* d_ws, size_t ws_size,
                              hipStream_t stream) {
  (void)in_sizes; (void)n_in; (void)out_size; (void)ws_size;
  const float* h       = (const float*)d_in[0];
  const float* wq_comp = (const float*)d_in[1];
  const float* wq_up   = (const float*)d_in[2];
  const float* wk      = (const float*)d_in[3];
  const float* wv      = (const float*)d_in[4];
  const float* qnw     = (const float*)d_in[5];
  const float* knw     = (const float*)d_in[6];
  const float* sink    = (const float*)d_in[7];
  const float* w1      = (const float*)d_in[8];
  const float* w2      = (const float*)d_in[9];
  float* out = (float*)d_out;
  bf16* ws   = (bf16*)d_ws;

  // ---- overlaid workspace (bf16 element offsets; peak 35.5M elems = 71 MB) ----
  const size_t M1 = 1048576;
  const size_t o_hb    = 0;               // [4096][2048] ph1-3
  const size_t o_qr    = 8*M1;            // [4096][2048] ph2-4
  const size_t o_w2T   = 0;               // [2048][8192] ph5 (hb,qr dead)
  const size_t o_qkv   = 16*M1;           // [4096][768]  ph2-3 (qc|k|v)
  const size_t o_WefT  = 16*M1;           // [2048][2048] ph5 (qkv dead)
  const size_t o_krt   = 20*M1;           // [4096][128]  ph3-4
  const size_t o_vt    = 20*M1 + 524288;  // [2][128][2048] ph3-4
  const size_t o_wqkvT = 21*M1;           // [768][2048]  ph1-3 (wqcT;wkT;wvT stacked)
  const size_t o_wquT  = 22*M1 + 524288;  // [2048][512]  ph1-2
  const size_t o_w1b   = 23*M1 + 524288;  // [4][512][2048] ph1-5
  const size_t o_x     = 27*M1 + 524288;  // [4096][2048] ph4-5

  const dim3 tb(256);
  // ---- ph1: conversions (merged: 2 launches) ----
  cvt4_all<<<dim3(12288), tb, 0, stream>>>(h, w1, ws+o_hb, ws+o_w1b);
  cvtT_all<<<dim3(2560), tb, 0, stream>>>(wq_comp, wk, wv, wq_up, ws+o_wqkvT, ws+o_wquT);

  // ---- ph2/3: [qc|k|v] = h @ [wqc|wk|wv] in ONE N=768 GEMM (m97 structure) ----
  gemm_bt<false><<<dim3(32, 6), tb, 0, stream>>>(ws+o_hb, ws+o_wqkvT, ws+o_qkv,
                                                 2048, 2048, 2048, 768, 0, 0, 0);
  // q = qc @ wq_up  (2-phase x 16-MFMA pipeline, XCD-swizzled)
  gemm_bt8<false><<<dim3(16, 16), dim3(512), 0, stream>>>(ws+o_qkv, ws+o_wquT, ws+o_qr,
                                                          512, 768, 512, 2048, 0, 0, 0);
  // rope+rms q (pre-scaled by 1/(sqrt(D)ln2)) and k in one launch
  rope_rms_all<<<dim3(17408), tb, 0, stream>>>(ws+o_qr, ws+o_qr, qnw,
                                               ws+o_qkv + 512, ws+o_krt, knw);
  // transpose v -> vt
  transpose_k<<<dim3(4, 64, 2), tb, 0, stream>>>(ws+o_qkv + 640, ws+o_vt, 2048, 128, 768, 2048,
                                                 (long long)2048*768, (long long)128*2048);

  // ---- ph4: attention ----
  attn_kernel<<<dim3(T_/64, H_, B_), tb, 0, stream>>>(ws+o_qr, ws+o_krt, ws+o_vt, sink, ws+o_x);

  // ---- ph5: WeffT = w2T_g @ w1_g^T per group (z=g), then out = x @ WeffT^T ----
  cvtT<<<dim3(64, 256), tb, 0, stream>>>(w2, ws+o_w2T, 8192, 2048);
  // 128x128 tiles -> (16,4,4)=256 blocks: full CU coverage (was 128 blocks at 1 block/CU)
  gemm_bt<false><<<dim3(16, 4, 4), tb, 0, stream>>>(ws+o_w2T, ws+o_w1b, ws+o_WefT,
                                                    2048, 8192, 2048, 2048,
                                                    2048, (long long)512*2048, 512);
  gemm_bt8<true><<<dim3(16, 16), dim3(512), 0, stream>>>(ws+o_x, ws+o_WefT, out,
                                                         2048, 2048, 2048, 2048, 0, 0, 0);
}

// Round 6
// 352.768 us; speedup vs baseline: 1.0302x; 1.0302x over previous
//
#include <hip/hip_runtime.h>
#include <hip/hip_bf16.h>
#include <stdint.h>

typedef __hip_bfloat16 bf16;
typedef __bf16 bf16x8 __attribute__((ext_vector_type(8)));
typedef float f32x4 __attribute__((ext_vector_type(4)));

#define B_ 2
#define T_ 2048
#define HID_ 2048
#define H_ 16
#define D_ 128
#define WIN_ 512

// ---- async global->LDS, 16B per lane (lds dest = wave-uniform base + lane*16) ----
__device__ __forceinline__ void async_copy16(const void* g, void* l) {
  __builtin_amdgcn_global_load_lds(
      (__attribute__((address_space(1))) void*)(uintptr_t)g,
      (__attribute__((address_space(3))) void*)(uint32_t)(uintptr_t)l,
      16, 0, 0);
}

// raw workgroup barrier with compiler memory fences (no vmcnt/lgkm drain)
__device__ __forceinline__ void block_sync() {
  asm volatile("" ::: "memory");
  __builtin_amdgcn_s_barrier();
  asm volatile("" ::: "memory");
}

// =================== fused fp32->bf16 (h and w1 in one launch) ===================
__global__ __launch_bounds__(256) void cvt4_all(
    const float* __restrict__ h, const float* __restrict__ w1, bf16* __restrict__ outh, bf16* __restrict__ outw1)
{
  int i = blockIdx.x * 256 + threadIdx.x;
  const int NH = 2097152;            // h: 2*2048*2048 /4
  const float* in; bf16* out;
  if (i < NH) { in = h; out = outh; }
  else { i -= NH; in = w1; out = outw1; }   // w1: 4*512*2048 /4 = 1048576
  const float4 v = ((const float4*)in)[i];
  bf16* p = out + (size_t)i * 4;
  p[0] = __float2bfloat16(v.x);
  p[1] = __float2bfloat16(v.y);
  p[2] = __float2bfloat16(v.z);
  p[3] = __float2bfloat16(v.w);
}

// =================== fused fp32->bf16 + transpose, 4 weight matrices in one launch ===================
__global__ __launch_bounds__(256) void cvtT_all(
    const float* __restrict__ wqc, const float* __restrict__ wk, const float* __restrict__ wv,
    const float* __restrict__ wqu, bf16* __restrict__ qkvT, bf16* __restrict__ wquT)
{
  __shared__ bf16 tile[32][33];
  const int id = blockIdx.x;
  const float* in; bf16* out; int R, C, bx, by;
  if (id < 1024)      { int l = id;        in = wqc; out = qkvT;                      R = 2048; C = 512;  bx = (l & 15) * 32; by = (l >> 4) * 32; }
  else if (id < 1280) { int l = id - 1024; in = wk;  out = qkvT + (size_t)512 * 2048; R = 2048; C = 128;  bx = (l & 3) * 32;  by = (l >> 2) * 32; }
  else if (id < 1536) { int l = id - 1280; in = wv;  out = qkvT + (size_t)640 * 2048; R = 2048; C = 128;  bx = (l & 3) * 32;  by = (l >> 2) * 32; }
  else                { int l = id - 1536; in = wqu; out = wquT;                      R = 512;  C = 2048; bx = (l & 63) * 32; by = (l >> 6) * 32; }
  const int tx = threadIdx.x & 31, ty = threadIdx.x >> 5;
#pragma unroll
  for (int i = 0; i < 32; i += 8)
    tile[ty+i][tx] = __float2bfloat16(in[(size_t)(by + ty + i)*C + bx + tx]);
  __syncthreads();
#pragma unroll
  for (int i = 0; i < 32; i += 8)
    out[(size_t)(bx + ty + i)*R + by + tx] = tile[tx][ty+i];
}

// =================== single fp32->bf16 transpose (w2) ===================
__global__ __launch_bounds__(256) void cvtT(
    const float* __restrict__ in, bf16* __restrict__ out, int R, int C)
{
  __shared__ bf16 tile[32][33];
  const int bx = blockIdx.x*32, by = blockIdx.y*32;
  const int tx = threadIdx.x & 31, ty = threadIdx.x >> 5;
#pragma unroll
  for (int i = 0; i < 32; i += 8)
    tile[ty+i][tx] = __float2bfloat16(in[(size_t)(by + ty + i)*C + bx + tx]);
  __syncthreads();
#pragma unroll
  for (int i = 0; i < 32; i += 8)
    out[(size_t)(bx + ty + i)*R + by + tx] = tile[tx][ty+i];
}

// =================== bf16 transpose: out[C][R] = in[R][C]^T (batched via z) ===================
__global__ __launch_bounds__(256) void transpose_k(
    const bf16* __restrict__ in, bf16* __restrict__ out,
    int R, int C, int ldin, int ldout, long long inBatch, long long outBatch)
{
  __shared__ bf16 tile[32][33];
  in  += (size_t)blockIdx.z * inBatch;
  out += (size_t)blockIdx.z * outBatch;
  const int bx = blockIdx.x*32, by = blockIdx.y*32;
  const int tx = threadIdx.x & 31, ty = threadIdx.x >> 5;
#pragma unroll
  for (int i = 0; i < 32; i += 8)
    tile[ty+i][tx] = in[(size_t)(by + ty + i)*ldin + bx + tx];
  __syncthreads();
#pragma unroll
  for (int i = 0; i < 32; i += 8)
    out[(size_t)(bx + ty + i)*ldout + by + tx] = tile[tx][ty+i];
}

// =================== bf16 GEMM (m97 structure): C[M,N] = A[M,K] * BT[N,K]^T ===================
// used for: qkv GEMM (N=768 -> 192 blocks) and Weff GEMM ((16,4,4)=256 blocks, full CU coverage)
template <bool F32OUT>
__global__ __launch_bounds__(256) void gemm_bt(
    const bf16* __restrict__ Ab, const bf16* __restrict__ Bb, void* __restrict__ Cb,
    int K, int lda, int ldb, int ldc,
    long long sAz, long long sBz, long long sCz)
{
  const bf16* A = Ab + (size_t)blockIdx.z * sAz;
  const bf16* B = Bb + (size_t)blockIdx.z * sBz;
  __shared__ __align__(16) __bf16 sa[128*64];
  __shared__ __align__(16) __bf16 sb[128*64];
  const int bm = blockIdx.x * 128, bn = blockIdx.y * 128;
  const int t = threadIdx.x;
  const int wave = t >> 6, lane = t & 63;
  const int fm = lane & 15, quad = lane >> 4;
  const int wm = (wave & 1) * 64, wn = (wave >> 1) * 64;
  const int arow0 = t >> 3;
  const int acol_sw = (((t & 7) ^ (arow0 & 7)) << 3);
  const int fsw = fm & 7;

  f32x4 acc[4][4];
#pragma unroll
  for (int i = 0; i < 4; ++i)
#pragma unroll
    for (int j = 0; j < 4; ++j) acc[i][j] = {0.f, 0.f, 0.f, 0.f};

  for (int k0 = 0; k0 < K; k0 += 64) {
    __syncthreads();
#pragma unroll
    for (int i = 0; i < 4; ++i)
      async_copy16(&A[(size_t)(bm + arow0 + i*32)*lda + k0 + acol_sw], &sa[(size_t)(i*256 + wave*64)*8]);
#pragma unroll
    for (int i = 0; i < 4; ++i)
      async_copy16(&B[(size_t)(bn + arow0 + i*32)*ldb + k0 + acol_sw], &sb[(size_t)(i*256 + wave*64)*8]);
    __syncthreads();
#pragma unroll
    for (int ks = 0; ks < 64; ks += 32) {
      bf16x8 av[4], bv[4];
#pragma unroll
      for (int mt = 0; mt < 4; ++mt)
        av[mt] = *(const bf16x8*)&sa[(wm + mt*16 + fm)*64 + ((((ks>>3) + quad) ^ fsw) << 3)];
#pragma unroll
      for (int nt = 0; nt < 4; ++nt)
        bv[nt] = *(const bf16x8*)&sb[(wn + nt*16 + fm)*64 + ((((ks>>3) + quad) ^ fsw) << 3)];
#pragma unroll
      for (int mt = 0; mt < 4; ++mt)
#pragma unroll
        for (int nt = 0; nt < 4; ++nt)
          acc[mt][nt] = __builtin_amdgcn_mfma_f32_16x16x32_bf16(av[mt], bv[nt], acc[mt][nt], 0, 0, 0);
    }
  }
  if constexpr (F32OUT) {
    float* C = (float*)Cb + (size_t)blockIdx.z * sCz;
#pragma unroll
    for (int mt = 0; mt < 4; ++mt)
#pragma unroll
      for (int r = 0; r < 4; ++r) {
        const int row = bm + wm + mt*16 + quad*4 + r;
#pragma unroll
        for (int nt = 0; nt < 4; ++nt)
          C[(size_t)row*ldc + bn + wn + nt*16 + fm] = acc[mt][nt][r];
      }
  } else {
    bf16* C = (bf16*)Cb + (size_t)blockIdx.z * sCz;
#pragma unroll
    for (int mt = 0; mt < 4; ++mt)
#pragma unroll
      for (int r = 0; r < 4; ++r) {
        const int row = bm + wm + mt*16 + quad*4 + r;
#pragma unroll
        for (int nt = 0; nt < 4; ++nt)
          C[(size_t)row*ldc + bn + wn + nt*16 + fm] = __float2bfloat16(acc[mt][nt][r]);
      }
  }
}

// =================== pipelined GEMM v2: 2 phases/K-tile, 16 MFMA/phase ===================
// BM=256, BN=128, BK=64; 512 threads = 8 waves; counted vmcnt(2) once per K-tile.
// NO blockIdx swizzle: round-4 A/B showed XCD-chunk swizzle inflates FETCH 41->70 GB-units
// (each XCD re-reads ALL of A); default round-robin already gives each XCD few A-panels.
template <bool F32OUT>
__global__ __launch_bounds__(512, 2) void gemm_bt8(
    const bf16* __restrict__ Ab, const bf16* __restrict__ Bb, void* __restrict__ Cb,
    int K, int lda, int ldb, int ldc,
    long long sAz, long long sBz, long long sCz)
{
  const bf16* A = Ab + (size_t)blockIdx.z * sAz;
  const bf16* B = Bb + (size_t)blockIdx.z * sBz;
  __shared__ __align__(16) __bf16 sA[2][256*64];
  __shared__ __align__(16) __bf16 sB[2][128*64];
  const int bm = blockIdx.x * 256, bn = blockIdx.y * 128;
  const int t = threadIdx.x;
  const int wave = t >> 6, lane = t & 63;
  const int fm = lane & 15, quad = lane >> 4, fsw = fm & 7;
  const int wave_m = wave >> 1, wave_n = wave & 1;
  const int srow = t >> 3;                      // staging row within a 64-row granule
  const int cchunk = (t & 7) ^ (srow & 7);      // pre-swizzled source chunk (inverse of read XOR)
  const int NT = K >> 6;                        // number of K-tiles (NT >= 2 required)

  auto stage = [&](int tile, int o) {           // o: 0=Bh0 1=Bh1 2=Ah0 3=Ah1
    if (tile >= NT) return;
    const int par = tile & 1;
    const int kc = (tile << 6) + (cchunk << 3);
    if (o < 2) {
      async_copy16(&B[(size_t)(bn + (o << 6) + srow)*ldb + kc],
                   &sB[par][(size_t)((o << 6) + wave*8) * 64]);
    } else {
      const int h = (o - 2) << 7;
      async_copy16(&A[(size_t)(bm + h + srow)*lda + kc],
                   &sA[par][(size_t)(h + wave*8) * 64]);
      async_copy16(&A[(size_t)(bm + h + 64 + srow)*lda + kc],
                   &sA[par][(size_t)(h + 64 + wave*8) * 64]);
    }
  };

  f32x4 acc[4][4];
#pragma unroll
  for (int i = 0; i < 4; ++i)
#pragma unroll
    for (int j = 0; j < 4; ++j) acc[i][j] = {0.f, 0.f, 0.f, 0.f};

  // prologue: A(0) 4, B(0) 2 (oldest 6), then B(1) 2; vmcnt(2) leaves B(1) in flight
  stage(0, 2); stage(0, 3); stage(0, 0); stage(0, 1);
  stage(1, 0); stage(1, 1);
  asm volatile("s_waitcnt vmcnt(2)" ::: "memory");
  block_sync();

  for (int d = 0; d < NT; ++d) {
    const int par = d & 1;
    bf16x8 bfr[4][2], a01[2][2], a23[2][2];
    // ---------------- phase 0: q-subtiles 0,1 ----------------
#pragma unroll
    for (int n = 0; n < 4; ++n) {
      const int brow = wave_n*64 + n*16 + fm;
      bfr[n][0] = *(const bf16x8*)&sB[par][(size_t)brow*64 + ((quad ^ fsw) << 3)];
      bfr[n][1] = *(const bf16x8*)&sB[par][(size_t)brow*64 + (((4 + quad) ^ fsw) << 3)];
    }
#pragma unroll
    for (int qq = 0; qq < 2; ++qq) {
      const int arow = wave_m*64 + qq*16 + fm;
      a01[qq][0] = *(const bf16x8*)&sA[par][(size_t)arow*64 + ((quad ^ fsw) << 3)];
      a01[qq][1] = *(const bf16x8*)&sA[par][(size_t)arow*64 + (((4 + quad) ^ fsw) << 3)];
    }
    stage(d + 1, 2); stage(d + 1, 3);
    block_sync();
    __builtin_amdgcn_s_setprio(1);
#pragma unroll
    for (int qq = 0; qq < 2; ++qq)
#pragma unroll
      for (int n = 0; n < 4; ++n) {
        acc[qq][n] = __builtin_amdgcn_mfma_f32_16x16x32_bf16(a01[qq][0], bfr[n][0], acc[qq][n], 0, 0, 0);
        acc[qq][n] = __builtin_amdgcn_mfma_f32_16x16x32_bf16(a01[qq][1], bfr[n][1], acc[qq][n], 0, 0, 0);
      }
    __builtin_amdgcn_s_setprio(0);
    block_sync();
    // ---------------- phase 1: q-subtiles 2,3 ----------------
#pragma unroll
    for (int qq = 0; qq < 2; ++qq) {
      const int arow = wave_m*64 + (2 + qq)*16 + fm;
      a23[qq][0] = *(const bf16x8*)&sA[par][(size_t)arow*64 + ((quad ^ fsw) << 3)];
      a23[qq][1] = *(const bf16x8*)&sA[par][(size_t)arow*64 + (((4 + quad) ^ fsw) << 3)];
    }
    stage(d + 2, 0); stage(d + 2, 1);
    block_sync();
    __builtin_amdgcn_s_setprio(1);
#pragma unroll
    for (int qq = 0; qq < 2; ++qq)
#pragma unroll
      for (int n = 0; n < 4; ++n) {
        acc[2+qq][n] = __builtin_amdgcn_mfma_f32_16x16x32_bf16(a23[qq][0], bfr[n][0], acc[2+qq][n], 0, 0, 0);
        acc[2+qq][n] = __builtin_amdgcn_mfma_f32_16x16x32_bf16(a23[qq][1], bfr[n][1], acc[2+qq][n], 0, 0, 0);
      }
    __builtin_amdgcn_s_setprio(0);
    if (d < NT - 1) {                     // per-K-tile checkpoint guarding tile d+1
      if (d == NT - 2) asm volatile("s_waitcnt vmcnt(0)" ::: "memory");
      else             asm volatile("s_waitcnt vmcnt(2)" ::: "memory");
    }
    block_sync();
  }

  if constexpr (F32OUT) {
    float* C = (float*)Cb + (size_t)blockIdx.z * sCz;
#pragma unroll
    for (int q = 0; q < 4; ++q)
#pragma unroll
      for (int r = 0; r < 4; ++r) {
        const int row = bm + wave_m*64 + q*16 + quad*4 + r;
#pragma unroll
        for (int n = 0; n < 4; ++n)
          C[(size_t)row*ldc + bn + wave_n*64 + n*16 + fm] = acc[q][n][r];
      }
  } else {
    bf16* C = (bf16*)Cb + (size_t)blockIdx.z * sCz;
#pragma unroll
    for (int q = 0; q < 4; ++q)
#pragma unroll
      for (int r = 0; r < 4; ++r) {
        const int row = bm + wave_m*64 + q*16 + quad*4 + r;
#pragma unroll
        for (int n = 0; n < 4; ++n)
          C[(size_t)row*ldc + bn + wave_n*64 + n*16 + fm] = __float2bfloat16(acc[q][n][r]);
      }
  }
}

// =================== fused partial-RoPE + RMSNorm, q and k paths in one launch ===================
__global__ __launch_bounds__(256) void rope_rms_all(
    const bf16* __restrict__ qin, bf16* __restrict__ qout, const float* __restrict__ qw,
    const bf16* __restrict__ kin, bf16* __restrict__ kout, const float* __restrict__ kw)
{
  int blk = blockIdx.x;
  const bf16* in; bf16* out; const float* w; int in_stride, t_shift; float oscale;
  if (blk < 16384) { in = qin; out = qout; w = qw; in_stride = 128; t_shift = 4; oscale = 0.12751744f; }
  else { blk -= 16384; in = kin; out = kout; w = kw; in_stride = 768; t_shift = 0; oscale = 1.0f; }
  const int rid = blk*4 + (threadIdx.x >> 6);
  const int lane = threadIdx.x & 63;
  const bf16* row = in + (size_t)rid * in_stride;
  float e0 = __bfloat162float(row[lane]);
  float e1 = __bfloat162float(row[lane + 64]);
  float s2 = e0*e0 + e1*e1;
#pragma unroll
  for (int off = 32; off; off >>= 1) s2 += __shfl_xor(s2, off);
  const float rms = rsqrtf(s2 * (1.f/128.f) + 1e-6f) * oscale;
  const int tpos = (rid >> t_shift) & (T_ - 1);
  const int i = lane & 31;
  const float inv = expf(-(float)i * 0.28782313662425574f);  // ln(10000)/32
  const float ang = (float)tpos * inv;
  float sn, c;
  sincosf(ang, &sn, &c);
  const float other = __shfl_xor(e0, 32);
  const float r0 = (lane < 32) ? (e0*c - other*sn) : (other*sn + e0*c);
  bf16* orow = out + (size_t)rid * 128;
  orow[lane]      = __float2bfloat16(r0 * rms * w[lane]);
  orow[lane + 64] = __float2bfloat16(e1 * rms * w[lane + 64]);
}

// =================== sliding-window flash attention (MQA, sink, max-free, swizzled LDS) ===================
// Swapped QK^T: lane holds P[q=fm][k=nt*16+quad*4+r]; P->LDS spill is 8 cvt_pk + 4 ds_write_b64
// into the sK alias (sK dead after QK; LDS 49152 B -> 3 blocks/CU). T14 reg-staged K/V prefetch.
// (Round-4's all-register P redistribution reverted: 12 shfl + ~24 cndmask cost more than the
// LDS round-trip it removed -- measured +1.6 us.)
__global__ __launch_bounds__(256, 3) void attn_kernel(
    const bf16* __restrict__ q,     // [B,T,H*D]  (pre-scaled by 1/(sqrt(D)ln2))
    const bf16* __restrict__ k,     // [B,T,D]
    const bf16* __restrict__ vt,    // [B,D,T]
    const float* __restrict__ sink, // [H]
    bf16* __restrict__ o)           // [B,T,H*D]
{
  __shared__ __align__(16) __bf16 sQ[64*128];   // 16 chunk-slots/row, swizzled ^(r&7)
  __shared__ __align__(16) __bf16 sK[64*128];   // post-QK: first 64*72 elems reused as P
  __shared__ __align__(16) __bf16 sV[128*64];   // [d][s], 8 slots/row, swizzled ^(d&7)
  const int qt = blockIdx.x, h = blockIdx.y, b = blockIdx.z;
  const int qb = qt * 64;
  const int t = threadIdx.x, wave = t >> 6, lane = t & 63;
  const int fm = lane & 15, quad = lane >> 4;
  const int fsw = fm & 7;
  const int qw = qb + wave*16;

#pragma unroll
  for (int i = 0; i < 4; ++i) {   // stage Q once (async, source-swizzled)
    int chunk = i*256 + t;
    int r = chunk >> 4, c8 = (chunk & 15) ^ (r & 7);
    async_copy16(&q[(size_t)((b*T_ + qb + r)*H_ + h)*D_ + c8*8], &sQ[(size_t)(i*256 + wave*64)*8]);
  }

  bf16x8 kreg[4], vreg[4];
  auto load_kv = [&](int kb) {     // source-swizzled (same layout the DMA produced)
#pragma unroll
    for (int i = 0; i < 4; ++i) {
      int chunk = i*256 + t;
      int r = chunk >> 4, c8 = (chunk & 15) ^ (r & 7);
      kreg[i] = *(const bf16x8*)&k[(size_t)(b*T_ + kb + r)*D_ + c8*8];
    }
#pragma unroll
    for (int i = 0; i < 4; ++i) {
      int chunk = i*256 + t;
      int d = chunk >> 3, c8 = (chunk & 7) ^ (d & 7);
      vreg[i] = *(const bf16x8*)&vt[(size_t)(b*D_ + d)*T_ + kb + c8*8];
    }
  };

  float l_part = 0.f;             // partial softmax denom for q = qb + wave*16 + fm
  f32x4 oacc[8];
#pragma unroll
  for (int i = 0; i < 8; ++i) oacc[i] = {0.f, 0.f, 0.f, 0.f};

  int lo = qb - (WIN_ - 1); if (lo < 0) lo = 0;
  const int kt0 = lo >> 6;
  load_kv(kt0 * 64);              // prologue prefetch

  for (int kt = kt0; kt <= qt; ++kt) {
    const int kb = kt * 64;
    // write K/V for this tile (compiler inserts counted vmcnt wait for kreg/vreg)
#pragma unroll
    for (int i = 0; i < 4; ++i)
      *(bf16x8*)&sK[(size_t)(i*256 + t)*8] = kreg[i];
#pragma unroll
    for (int i = 0; i < 4; ++i)
      *(bf16x8*)&sV[(size_t)(i*256 + t)*8] = vreg[i];
    asm volatile("s_waitcnt lgkmcnt(0)" ::: "memory");
    block_sync();                 // K/V (and Q, 1st iter) visible to all waves
    if (kt < qt) load_kv(kb + 64);  // prefetch next tile under QK+softmax+PV

    // S^T strip: s[nt][r] = S[k = kb+nt*16+quad*4+r][q = qb+wave*16+fm]  (swapped operands)
    f32x4 s[4];
#pragma unroll
    for (int nt = 0; nt < 4; ++nt) s[nt] = {0.f, 0.f, 0.f, 0.f};
#pragma unroll
    for (int ds = 0; ds < 4; ++ds) {
      bf16x8 aq = *(const bf16x8*)&sQ[(wave*16 + fm)*128 + (((ds*4 + quad) ^ fsw) << 3)];
#pragma unroll
      for (int nt = 0; nt < 4; ++nt) {
        bf16x8 bk = *(const bf16x8*)&sK[(nt*16 + fm)*128 + (((ds*4 + quad) ^ fsw) << 3)];
        s[nt] = __builtin_amdgcn_mfma_f32_16x16x32_bf16(bk, aq, s[nt], 0, 0, 0);  // SWAPPED
      }
    }
    block_sync();                 // all waves' QK reads of sK done before P overwrites it

    const bool interior = (kb + 63 <= qw) && (kb >= qw - (WIN_ - 16));
    if (!interior) {
      const int qi = qb + wave*16 + fm;
#pragma unroll
      for (int nt = 0; nt < 4; ++nt)
#pragma unroll
        for (int r = 0; r < 4; ++r) {
          const int ki = kb + nt*16 + quad*4 + r;
          const bool ok = (ki <= qi) && (qi - ki < WIN_);
          s[nt][r] = ok ? s[nt][r] : -1e30f;
        }
    }
#pragma unroll
    for (int nt = 0; nt < 4; ++nt)
#pragma unroll
      for (int r = 0; r < 4; ++r) {
        s[nt][r] = __builtin_exp2f(s[nt][r]);
        l_part += s[nt][r];
      }
    // packed P-write: row q (wave-private), cols nt*16 + quad*4 + {0..3}
#pragma unroll
    for (int nt = 0; nt < 4; ++nt) {
      uint32_t plo, phi;
      asm("v_cvt_pk_bf16_f32 %0, %1, %2" : "=v"(plo) : "v"(s[nt][0]), "v"(s[nt][1]));
      asm("v_cvt_pk_bf16_f32 %0, %1, %2" : "=v"(phi) : "v"(s[nt][2]), "v"(s[nt][3]));
      uint2 pw; pw.x = plo; pw.y = phi;
      *(uint2*)&sK[(wave*16 + fm)*72 + nt*16 + quad*4] = pw;
    }
    asm volatile("s_waitcnt lgkmcnt(0)" ::: "memory");
    // O += P V  (ap reads wave-private P rows)
#pragma unroll
    for (int ks = 0; ks < 2; ++ks) {
      bf16x8 ap = *(const bf16x8*)&sK[(wave*16 + fm)*72 + ks*32 + quad*8];  // P alias
#pragma unroll
      for (int nt = 0; nt < 8; ++nt) {
        bf16x8 bv = *(const bf16x8*)&sV[(nt*16 + fm)*64 + (((ks*4 + quad) ^ fsw) << 3)];
        oacc[nt] = __builtin_amdgcn_mfma_f32_16x16x32_bf16(ap, bv, oacc[nt], 0, 0, 0);
      }
    }
    block_sync();                 // all PV reads of the alias done before next K ds_writes
  }
  // reduce l across quads (lanes with same fm), then redistribute to output rows
  l_part += __shfl_xor(l_part, 16);
  l_part += __shfl_xor(l_part, 32);   // now l_part = L[q = qb + wave*16 + fm]
  const float sink_p = __builtin_exp2f(sink[h] * 1.4426950408889634f);
#pragma unroll
  for (int r = 0; r < 4; ++r) {
    const int qi = qb + wave*16 + quad*4 + r;
    const float inv_l = 1.f / (__shfl(l_part, quad*4 + r) + sink_p);
#pragma unroll
    for (int nt = 0; nt < 8; ++nt) {
      const int d = nt*16 + fm;
      o[(size_t)(b*T_ + qi)*(H_*D_) + h*D_ + d] = __float2bfloat16(oacc[nt][r] * inv_l);
    }
  }
}

// =========================================================================================
extern "C" void kernel_launch(void* const* d_in, const int* in_sizes, int n_in,
                              void* d_out, int out_size, void* d_ws, size_t ws_size,
                              hipStream_t stream) {
  (void)in_sizes; (void)n_in; (void)out_size; (void)ws_size;
  const float* h       = (const float*)d_in[0];
  const float* wq_comp = (const float*)d_in[1];
  const float* wq_up   = (const float*)d_in[2];
  const float* wk      = (const float*)d_in[3];
  const float* wv      = (const float*)d_in[4];
  const float* qnw     = (const float*)d_in[5];
  const float* knw     = (const float*)d_in[6];
  const float* sink    = (const float*)d_in[7];
  const float* w1      = (const float*)d_in[8];
  const float* w2      = (const float*)d_in[9];
  float* out = (float*)d_out;
  bf16* ws   = (bf16*)d_ws;

  // ---- overlaid workspace (bf16 element offsets; peak 35.5M elems = 71 MB) ----
  const size_t M1 = 1048576;
  const size_t o_hb    = 0;               // [4096][2048] ph1-3
  const size_t o_qr    = 8*M1;            // [4096][2048] ph2-4
  const size_t o_w2T   = 0;               // [2048][8192] ph5 (hb,qr dead)
  const size_t o_qkv   = 16*M1;           // [4096][768]  ph2-3 (qc|k|v)
  const size_t o_WefT  = 16*M1;           // [2048][2048] ph5 (qkv dead)
  const size_t o_krt   = 20*M1;           // [4096][128]  ph3-4
  const size_t o_vt    = 20*M1 + 524288;  // [2][128][2048] ph3-4
  const size_t o_wqkvT = 21*M1;           // [768][2048]  ph1-3 (wqcT;wkT;wvT stacked)
  const size_t o_wquT  = 22*M1 + 524288;  // [2048][512]  ph1-2
  const size_t o_w1b   = 23*M1 + 524288;  // [4][512][2048] ph1-5
  const size_t o_x     = 27*M1 + 524288;  // [4096][2048] ph4-5

  const dim3 tb(256);
  // ---- ph1: conversions (merged: 2 launches) ----
  cvt4_all<<<dim3(12288), tb, 0, stream>>>(h, w1, ws+o_hb, ws+o_w1b);
  cvtT_all<<<dim3(2560), tb, 0, stream>>>(wq_comp, wk, wv, wq_up, ws+o_wqkvT, ws+o_wquT);

  // ---- ph2/3: [qc|k|v] = h @ [wqc|wk|wv] in ONE N=768 GEMM (m97 structure) ----
  gemm_bt<false><<<dim3(32, 6), tb, 0, stream>>>(ws+o_hb, ws+o_wqkvT, ws+o_qkv,
                                                 2048, 2048, 2048, 768, 0, 0, 0);
  // q = qc @ wq_up  (2-phase x 16-MFMA pipeline)
  gemm_bt8<false><<<dim3(16, 16), dim3(512), 0, stream>>>(ws+o_qkv, ws+o_wquT, ws+o_qr,
                                                          512, 768, 512, 2048, 0, 0, 0);
  // rope+rms q (pre-scaled by 1/(sqrt(D)ln2)) and k in one launch
  rope_rms_all<<<dim3(17408), tb, 0, stream>>>(ws+o_qr, ws+o_qr, qnw,
                                               ws+o_qkv + 512, ws+o_krt, knw);
  // transpose v -> vt
  transpose_k<<<dim3(4, 64, 2), tb, 0, stream>>>(ws+o_qkv + 640, ws+o_vt, 2048, 128, 768, 2048,
                                                 (long long)2048*768, (long long)128*2048);

  // ---- ph4: attention ----
  attn_kernel<<<dim3(T_/64, H_, B_), tb, 0, stream>>>(ws+o_qr, ws+o_krt, ws+o_vt, sink, ws+o_x);

  // ---- ph5: WeffT = w2T_g @ w1_g^T per group (z=g), then out = x @ WeffT^T ----
  cvtT<<<dim3(64, 256), tb, 0, stream>>>(w2, ws+o_w2T, 8192, 2048);
  // 128x128 tiles -> (16,4,4)=256 blocks: full CU coverage (was 128 blocks at 1 block/CU)
  gemm_bt<false><<<dim3(16, 4, 4), tb, 0, stream>>>(ws+o_w2T, ws+o_w1b, ws+o_WefT,
                                                    2048, 8192, 2048, 2048,
                                                    2048, (long long)512*2048, 512);
  gemm_bt8<true><<<dim3(16, 16), dim3(512), 0, stream>>>(ws+o_x, ws+o_WefT, out,
                                                         2048, 2048, 2048, 2048, 0, 0, 0);
}